// Round 6
// baseline (436.571 us; speedup 1.0000x reference)
//
#include <hip/hip_runtime.h>
#include <math.h>

#define Ss 1024
#define Dd 1024
#define Hh 16
#define Kk 64

typedef __bf16 bf16x8 __attribute__((ext_vector_type(8)));
typedef __bf16 bf16x4 __attribute__((ext_vector_type(4)));
typedef float  f32x4  __attribute__((ext_vector_type(4)));

#define MFMA16(a, b, c) __builtin_amdgcn_mfma_f32_16x16x32_bf16(a, b, c, 0, 0, 0)

// ws element offsets (bf16 units): WT | WoT | qb | kb | vb | ctxb
#define WT_E   3145728u
#define WOT_E  1048576u
#define QKV_E  8388608u

__device__ __forceinline__ bf16x8 pack8(float4 a, float4 b) {
    return (bf16x8){(__bf16)a.x, (__bf16)a.y, (__bf16)a.z, (__bf16)a.w,
                    (__bf16)b.x, (__bf16)b.y, (__bf16)b.z, (__bf16)b.w};
}

// ---------------------------------------------------------------------------
// prep: transpose+cast weight matrix z (x-cast now folded into gemm staging)
// ---------------------------------------------------------------------------
__global__ __launch_bounds__(256) void prep(
    const float* __restrict__ Wq, const float* __restrict__ Wk,
    const float* __restrict__ Wv, const float* __restrict__ Wo,
    __bf16* __restrict__ WT, __bf16* __restrict__ WoT)
{
    __shared__ float tile[64][65];
    const int z = blockIdx.z;
    const int t = threadIdx.x;

    const float* src = (z == 0) ? Wq : (z == 1) ? Wk : (z == 2) ? Wv : Wo;
    __bf16* dst = (z < 3) ? (WT + (size_t)z * 1048576) : WoT;

    int r0 = blockIdx.y * 64, c0 = blockIdx.x * 64;
    int rr = t >> 2, cg = (t & 3) * 16;

    #pragma unroll
    for (int u = 0; u < 4; ++u) {
        float4 v = *(const float4*)(src + (size_t)(r0 + rr) * 1024 + c0 + cg + u * 4);
        tile[rr][cg + u * 4 + 0] = v.x;
        tile[rr][cg + u * 4 + 1] = v.y;
        tile[rr][cg + u * 4 + 2] = v.z;
        tile[rr][cg + u * 4 + 3] = v.w;
    }
    __syncthreads();
    bf16x8 o0, o1;
    #pragma unroll
    for (int jj = 0; jj < 8; ++jj) o0[jj] = (__bf16)tile[cg + jj][rr];
    #pragma unroll
    for (int jj = 0; jj < 8; ++jj) o1[jj] = (__bf16)tile[cg + 8 + jj][rr];
    __bf16* dp = dst + (size_t)(c0 + rr) * 1024 + r0 + cg;
    *(bf16x8*)dp = o0;
    *(bf16x8*)(dp + 8) = o1;
}

// ---------------------------------------------------------------------------
// bf16 MFMA GEMM, 128x128 tile, BK=32, ping-pong LDS dbuf (1 barrier/iter).
// Operand-SWAPPED MFMA (D = W_frag . x_frag) for Q/K/out so the C-fragment's
// reg-contiguity lands along the output-contiguous dim (ch/d) -> vector
// stores. V third keeps unswapped orientation (reg-contiguity along s for
// the transposed [ch][s] layout).
// mode 0: A = x fp32 (cast folded into staging); QKV epilogue, Q pre-scaled.
// mode 1: A = ctx bf16; fp32 out + bias, float4 stores.
// ---------------------------------------------------------------------------
__global__ __launch_bounds__(256) void gemm_bt(
    const void* __restrict__ Av, const __bf16* __restrict__ Bt, int mode,
    __bf16* __restrict__ qb, __bf16* __restrict__ kb, __bf16* __restrict__ vb,
    const float* __restrict__ bq, const float* __restrict__ bk,
    const float* __restrict__ bv,
    float* __restrict__ outf, const float* __restrict__ bo)
{
    __shared__ __align__(16) __bf16 As[2][128][32];
    __shared__ __align__(16) __bf16 Bs[2][128][32];

    const int t = threadIdx.x;
    const int wave = t >> 6, lane = t & 63;
    const int quad = lane >> 4, l16 = lane & 15;
    const int wm = wave >> 1, wn = wave & 1;
    const int m0 = blockIdx.y * 128, n0 = blockIdx.x * 128;

    const int sr = t >> 2;          // staging row 0..63
    const int sc = (t & 3) * 8;     // staging col (elements)

    const int z = (mode == 0) ? (n0 >> 10) : 3;
    const bool swp = (z != 2);      // V keeps unswapped orientation

    f32x4 acc[4][4];
    #pragma unroll
    for (int i = 0; i < 4; ++i)
        #pragma unroll
        for (int j = 0; j < 4; ++j) acc[i][j] = (f32x4){0.f, 0.f, 0.f, 0.f};

    const float*  Af = (const float*)Av;
    const __bf16* Ab = (const __bf16*)Av;
    const __bf16* pb0 = Bt + (size_t)(n0 + sr) * 1024 + sc;
    const __bf16* pb1 = Bt + (size_t)(n0 + sr + 64) * 1024 + sc;

    // prefetch regs
    float4 fa0a, fa0b, fa1a, fa1b;      // mode 0 (fp32 A)
    bf16x8 ra0, ra1;                    // mode 1 (bf16 A)
    bf16x8 rb0, rb1;

    if (mode == 0) {
        const float* p0 = Af + (size_t)(m0 + sr) * 1024 + sc;
        const float* p1 = Af + (size_t)(m0 + sr + 64) * 1024 + sc;
        fa0a = *(const float4*)(p0);     fa0b = *(const float4*)(p0 + 4);
        fa1a = *(const float4*)(p1);     fa1b = *(const float4*)(p1 + 4);
    } else {
        ra0 = *(const bf16x8*)(Ab + (size_t)(m0 + sr) * 1024 + sc);
        ra1 = *(const bf16x8*)(Ab + (size_t)(m0 + sr + 64) * 1024 + sc);
    }
    rb0 = *(const bf16x8*)(pb0);
    rb1 = *(const bf16x8*)(pb1);

    for (int k0 = 0; k0 < 1024; k0 += 32) {
        const int p = (k0 >> 5) & 1;
        if (mode == 0) {
            *(bf16x8*)&As[p][sr][sc] = pack8(fa0a, fa0b);
            *(bf16x8*)&As[p][sr + 64][sc] = pack8(fa1a, fa1b);
        } else {
            *(bf16x8*)&As[p][sr][sc] = ra0;
            *(bf16x8*)&As[p][sr + 64][sc] = ra1;
        }
        *(bf16x8*)&Bs[p][sr][sc] = rb0;
        *(bf16x8*)&Bs[p][sr + 64][sc] = rb1;
        __syncthreads();

        const int kn = k0 + 32;
        if (kn < 1024) {   // issue next chunk's loads; overlap compute below
            if (mode == 0) {
                const float* p0 = Af + (size_t)(m0 + sr) * 1024 + kn + sc;
                const float* p1 = Af + (size_t)(m0 + sr + 64) * 1024 + kn + sc;
                fa0a = *(const float4*)(p0);     fa0b = *(const float4*)(p0 + 4);
                fa1a = *(const float4*)(p1);     fa1b = *(const float4*)(p1 + 4);
            } else {
                ra0 = *(const bf16x8*)(Ab + (size_t)(m0 + sr) * 1024 + kn + sc);
                ra1 = *(const bf16x8*)(Ab + (size_t)(m0 + sr + 64) * 1024 + kn + sc);
            }
            rb0 = *(const bf16x8*)(pb0 + kn);
            rb1 = *(const bf16x8*)(pb1 + kn);
        }

        bf16x8 af[4], bfr[4];
        #pragma unroll
        for (int i = 0; i < 4; ++i)
            af[i] = *(const bf16x8*)&As[p][wm * 64 + i * 16 + l16][quad * 8];
        #pragma unroll
        for (int j = 0; j < 4; ++j)
            bfr[j] = *(const bf16x8*)&Bs[p][wn * 64 + j * 16 + l16][quad * 8];
        if (swp) {
            #pragma unroll
            for (int i = 0; i < 4; ++i)
                #pragma unroll
                for (int j = 0; j < 4; ++j)
                    acc[i][j] = MFMA16(bfr[j], af[i], acc[i][j]);   // D[n][m]
        } else {
            #pragma unroll
            for (int i = 0; i < 4; ++i)
                #pragma unroll
                for (int j = 0; j < 4; ++j)
                    acc[i][j] = MFMA16(af[i], bfr[j], acc[i][j]);   // D[m][n]
        }
    }

    if (mode == 0) {
        const float* bias = (z == 0) ? bq : (z == 1) ? bk : bv;
        if (z < 2) {
            // swapped: reg r -> ch+r (contiguous), l16 -> token s
            __bf16* dst0 = (z == 0) ? qb : kb;
            const float sc2 = (z == 0) ? 0.125f : 1.0f;
            const int h = ((n0 & 1023) >> 6) + wn;
            #pragma unroll
            for (int i = 0; i < 4; ++i) {
                int m = m0 + wm * 64 + i * 16 + l16;
                int b = m >> 10, s = m & 1023;
                __bf16* dst = dst0 + ((size_t)(b * Hh + h) * Ss + s) * Kk;
                #pragma unroll
                for (int j = 0; j < 4; ++j) {
                    int ch0 = j * 16 + quad * 4;
                    float4 b4 = *(const float4*)(bias + (n0 & 1023) + wn * 64 + ch0);
                    bf16x4 o;
                    o[0] = (__bf16)((acc[i][j][0] + b4.x) * sc2);
                    o[1] = (__bf16)((acc[i][j][1] + b4.y) * sc2);
                    o[2] = (__bf16)((acc[i][j][2] + b4.z) * sc2);
                    o[3] = (__bf16)((acc[i][j][3] + b4.w) * sc2);
                    *(bf16x4*)(dst + ch0) = o;
                }
            }
        } else {
            // unswapped (V): reg r -> token s+r (contiguous in [ch][s] layout)
            #pragma unroll
            for (int i = 0; i < 4; ++i) {
                int row = m0 + wm * 64 + i * 16 + quad * 4;
                int b = row >> 10, s = row & 1023;
                #pragma unroll
                for (int j = 0; j < 4; ++j) {
                    int n1 = (n0 + wn * 64 + j * 16 + l16) & 1023;
                    int h = n1 >> 6, ch = n1 & 63;
                    float bia = bv[n1];
                    bf16x4 o;
                    #pragma unroll
                    for (int r = 0; r < 4; ++r) o[r] = (__bf16)(acc[i][j][r] + bia);
                    *(bf16x4*)(vb + ((size_t)(b * Hh + h) * Kk + ch) * Ss + s) = o;
                }
            }
        }
    } else {
        // swapped: reg r -> d+r contiguous -> float4 stores
        #pragma unroll
        for (int i = 0; i < 4; ++i) {
            int m = m0 + wm * 64 + i * 16 + l16;
            #pragma unroll
            for (int j = 0; j < 4; ++j) {
                int n = n0 + wn * 64 + j * 16 + quad * 4;
                float4 b4 = *(const float4*)(bo + n);
                float4 o;
                o.x = acc[i][j][0] + b4.x;
                o.y = acc[i][j][1] + b4.y;
                o.z = acc[i][j][2] + b4.z;
                o.w = acc[i][j][3] + b4.w;
                *(float4*)(outf + (size_t)m * 1024 + n) = o;
            }
        }
    }
}

// ---------------------------------------------------------------------------
// Flash attention: fixed-base softmax, wave-private P, 32 q/wave, direct
// global Q fragments (no Qs tile), bf16 mask, swapped PV (O ch-major ->
// bf16x4 ctx stores). LDS 38.5 KB -> 4 blocks/CU.
// ---------------------------------------------------------------------------
__global__ __launch_bounds__(256) void attn(
    const __bf16* __restrict__ qb, const __bf16* __restrict__ kb,
    const __bf16* __restrict__ vb, const int* __restrict__ mask,
    __bf16* __restrict__ ctx)
{
    const int bh = blockIdx.x;
    const int q0 = blockIdx.y * 128;
    const int b  = bh >> 4;
    const int h  = bh & 15;
    const size_t base = (size_t)bh * Ss * Kk;

    __shared__ __align__(16) __bf16 Ks[64][72];
    __shared__ __align__(16) __bf16 VTs[64][72];
    __shared__ __align__(16) __bf16 Ps[4][32][72];
    __shared__ __bf16 mkb[1024];
    __shared__ float  lds_l[4][32];

    const int t    = threadIdx.x;
    const int wave = t >> 6, lane = t & 63;
    const int quad = lane >> 4, l16 = lane & 15;
    const int qbase = wave * 32;

    // stage mask as bf16 0/1
    {
        int4 mi = *(const int4*)(mask + b * Ss + t * 4);
        mkb[t * 4 + 0] = (__bf16)(float)mi.x;
        mkb[t * 4 + 1] = (__bf16)(float)mi.y;
        mkb[t * 4 + 2] = (__bf16)(float)mi.z;
        mkb[t * 4 + 3] = (__bf16)(float)mi.w;
    }

    // K/V tile-0 prefetch
    const int r0 = t >> 3, c0 = (t & 7) * 8;
    bf16x8 kr0, kr1, vr0, vr1;
    kr0 = *(const bf16x8*)(kb + base + (size_t)(r0) * Kk + c0);
    kr1 = *(const bf16x8*)(kb + base + (size_t)(r0 + 32) * Kk + c0);
    vr0 = *(const bf16x8*)(vb + base + (size_t)(r0) * Ss + c0);
    vr1 = *(const bf16x8*)(vb + base + (size_t)(r0 + 32) * Ss + c0);

    // Q A-fragments direct from global (row l16, 4 quads cover 64B lines)
    bf16x8 aq[2][2];
    #pragma unroll
    for (int rg = 0; rg < 2; ++rg) {
        const __bf16* qr = qb + base + (size_t)(q0 + qbase + rg * 16 + l16) * Kk;
        aq[rg][0] = *(const bf16x8*)(qr + quad * 8);
        aq[rg][1] = *(const bf16x8*)(qr + 32 + quad * 8);
    }

    __syncthreads();   // mkb visible

    float mqf[2][4], omqf[2][4];
    #pragma unroll
    for (int rg = 0; rg < 2; ++rg)
        #pragma unroll
        for (int i = 0; i < 4; ++i) {
            float m = (float)mkb[q0 + qbase + rg * 16 + quad * 4 + i];
            mqf[rg][i] = m; omqf[rg][i] = 1.0f - m;
        }

    f32x4 O[2][4];     // swapped PV: O[rg][cb]: m=ch(cb*16+quad*4+r), n=q(l16)
    float lsum[2][4];
    #pragma unroll
    for (int rg = 0; rg < 2; ++rg)
        #pragma unroll
        for (int nb = 0; nb < 4; ++nb) O[rg][nb] = (f32x4){0.f, 0.f, 0.f, 0.f};
    #pragma unroll
    for (int rg = 0; rg < 2; ++rg)
        #pragma unroll
        for (int i = 0; i < 4; ++i) lsum[rg][i] = 0.f;

    for (int kt = 0; kt < Ss; kt += 64) {
        __syncthreads();
        *(bf16x8*)&Ks[r0][c0] = kr0;
        *(bf16x8*)&Ks[r0 + 32][c0] = kr1;
        *(bf16x8*)&VTs[r0][c0] = vr0;
        *(bf16x8*)&VTs[r0 + 32][c0] = vr1;
        __syncthreads();

        int ktn = kt + 64;
        if (ktn < Ss) {
            kr0 = *(const bf16x8*)(kb + base + (size_t)(ktn + r0) * Kk + c0);
            kr1 = *(const bf16x8*)(kb + base + (size_t)(ktn + r0 + 32) * Kk + c0);
            vr0 = *(const bf16x8*)(vb + base + (size_t)(r0) * Ss + ktn + c0);
            vr1 = *(const bf16x8*)(vb + base + (size_t)(r0 + 32) * Ss + ktn + c0);
        }

        float mkv[4];
        #pragma unroll
        for (int nb = 0; nb < 4; ++nb) mkv[nb] = (float)mkb[kt + nb * 16 + l16];

        bf16x8 kb0[4], kb1[4];
        #pragma unroll
        for (int nb = 0; nb < 4; ++nb) {
            kb0[nb] = *(const bf16x8*)&Ks[nb * 16 + l16][quad * 8];
            kb1[nb] = *(const bf16x8*)&Ks[nb * 16 + l16][32 + quad * 8];
        }

        // scores: C layout row=q(quad*4+i), col=key(nb*16+l16)
        f32x4 s[2][4];
        #pragma unroll
        for (int rg = 0; rg < 2; ++rg)
            #pragma unroll
            for (int nb = 0; nb < 4; ++nb) {
                f32x4 a = (f32x4){0.f, 0.f, 0.f, 0.f};
                a = MFMA16(aq[rg][0], kb0[nb], a);
                a = MFMA16(aq[rg][1], kb1[nb], a);
                s[rg][nb] = a;
            }

        // fixed-base softmax: p = mq ? (mk ? exp(s) : 0) : 1
        #pragma unroll
        for (int rg = 0; rg < 2; ++rg)
            #pragma unroll
            for (int i = 0; i < 4; ++i) {
                float ls = 0.f;
                #pragma unroll
                for (int nb = 0; nb < 4; ++nb) {
                    float p = __expf(s[rg][nb][i]) * mkv[nb];
                    p = p * mqf[rg][i] + omqf[rg][i];
                    Ps[wave][rg * 16 + quad * 4 + i][nb * 16 + l16] = (__bf16)p;
                    ls += p;
                }
                lsum[rg][i] += ls;
            }

        // P fragments (wave-private LDS, no barrier)
        bf16x8 ap0[2], ap1[2];
        #pragma unroll
        for (int rg = 0; rg < 2; ++rg) {
            ap0[rg] = *(const bf16x8*)&Ps[wave][rg * 16 + l16][quad * 8];
            ap1[rg] = *(const bf16x8*)&Ps[wave][rg * 16 + l16][32 + quad * 8];
        }
        // PV swapped: O[ch][q] += VT_frag . P_frag
        #pragma unroll
        for (int nb = 0; nb < 4; ++nb) {
            bf16x8 vb0 = *(const bf16x8*)&VTs[nb * 16 + l16][quad * 8];
            bf16x8 vb1 = *(const bf16x8*)&VTs[nb * 16 + l16][32 + quad * 8];
            #pragma unroll
            for (int rg = 0; rg < 2; ++rg) {
                O[rg][nb] = MFMA16(vb0, ap0[rg], O[rg][nb]);
                O[rg][nb] = MFMA16(vb1, ap1[rg], O[rg][nb]);
            }
        }
    }

    // l per q-row -> broadcast across lanes via wave-private LDS
    #pragma unroll
    for (int rg = 0; rg < 2; ++rg)
        #pragma unroll
        for (int i = 0; i < 4; ++i) {
            float l = lsum[rg][i];
            l += __shfl_xor(l, 1);
            l += __shfl_xor(l, 2);
            l += __shfl_xor(l, 4);
            l += __shfl_xor(l, 8);
            if (l16 == 0) lds_l[wave][rg * 16 + quad * 4 + i] = l;
        }
    float invl[2];
    #pragma unroll
    for (int rg = 0; rg < 2; ++rg) invl[rg] = 1.0f / lds_l[wave][rg * 16 + l16];

    // epilogue: O is ch-major per lane -> bf16x4 contiguous-ch stores
    #pragma unroll
    for (int rg = 0; rg < 2; ++rg) {
        int q = q0 + qbase + rg * 16 + l16;
        __bf16* dst = ctx + ((size_t)(b * Ss + q) * Hh + h) * Kk;
        #pragma unroll
        for (int nb = 0; nb < 4; ++nb) {
            bf16x4 o;
            o[0] = (__bf16)(O[rg][nb][0] * invl[rg]);
            o[1] = (__bf16)(O[rg][nb][1] * invl[rg]);
            o[2] = (__bf16)(O[rg][nb][2] * invl[rg]);
            o[3] = (__bf16)(O[rg][nb][3] * invl[rg]);
            *(bf16x4*)(dst + nb * 16 + quad * 4) = o;
        }
    }
}

extern "C" void kernel_launch(void* const* d_in, const int* in_sizes, int n_in,
                              void* d_out, int out_size, void* d_ws, size_t ws_size,
                              hipStream_t stream) {
    const float* x    = (const float*)d_in[0];
    const int*   mask = (const int*)d_in[1];
    const float* Wq   = (const float*)d_in[2];
    const float* bq   = (const float*)d_in[3];
    const float* Wk   = (const float*)d_in[4];
    const float* bk   = (const float*)d_in[5];
    const float* Wv   = (const float*)d_in[6];
    const float* bv   = (const float*)d_in[7];
    const float* Wo   = (const float*)d_in[8];
    const float* bo   = (const float*)d_in[9];

    __bf16* WT   = (__bf16*)d_ws;
    __bf16* WoT  = WT + WT_E;
    __bf16* qb   = WoT + WOT_E;
    __bf16* kb   = qb + QKV_E;
    __bf16* vb   = kb + QKV_E;
    __bf16* ctxb = vb + QKV_E;
    float* out = (float*)d_out;

    prep<<<dim3(16, 16, 4), 256, 0, stream>>>(Wq, Wk, Wv, Wo, WT, WoT);
    gemm_bt<<<dim3(24, 64), 256, 0, stream>>>(x, WT, 0, qb, kb, vb,
                                              bq, bk, bv, nullptr, nullptr);
    attn<<<dim3(128, 8), 256, 0, stream>>>(qb, kb, vb, mask, ctxb);
    gemm_bt<<<dim3(8, 64), 256, 0, stream>>>(ctxb, WoT, 1, nullptr, nullptr,
                                             nullptr, nullptr, nullptr, nullptr,
                                             out, bo);
}

// Round 7
// 335.315 us; speedup vs baseline: 1.3020x; 1.3020x over previous
//
#include <hip/hip_runtime.h>
#include <math.h>

#define Ss 1024
#define Dd 1024
#define Hh 16
#define Kk 64

typedef __bf16 bf16x8 __attribute__((ext_vector_type(8)));
typedef __bf16 bf16x4 __attribute__((ext_vector_type(4)));
typedef float  f32x4  __attribute__((ext_vector_type(4)));

#define MFMA16(a, b, c) __builtin_amdgcn_mfma_f32_16x16x32_bf16(a, b, c, 0, 0, 0)

// ws element offsets (bf16 units): xb | WT | WoT | qb | kb | vb | ctxb
#define XB_E   8388608u
#define WT_E   3145728u
#define WOT_E  1048576u
#define QKV_E  8388608u

// ---------------------------------------------------------------------------
// prep: z<4 -> transpose+cast weight matrix z; z==4 -> cast x to bf16
// ---------------------------------------------------------------------------
__global__ __launch_bounds__(256) void prep(
    const float* __restrict__ x,
    const float* __restrict__ Wq, const float* __restrict__ Wk,
    const float* __restrict__ Wv, const float* __restrict__ Wo,
    __bf16* __restrict__ xb, __bf16* __restrict__ WT, __bf16* __restrict__ WoT)
{
    __shared__ float tile[64][65];
    const int z = blockIdx.z;
    const int t = threadIdx.x;

    if (z == 4) {   // x cast: 256 blocks, 32768 floats each
        size_t blk = blockIdx.y * 16 + blockIdx.x;
        const float4* src = (const float4*)(x + blk * 32768);
        bf16x4* dst = (bf16x4*)(xb + blk * 32768);
        #pragma unroll
        for (int u = 0; u < 32; ++u) {
            float4 v = src[u * 256 + t];
            dst[u * 256 + t] =
                (bf16x4){(__bf16)v.x, (__bf16)v.y, (__bf16)v.z, (__bf16)v.w};
        }
        return;
    }

    const float* src = (z == 0) ? Wq : (z == 1) ? Wk : (z == 2) ? Wv : Wo;
    __bf16* dst = (z < 3) ? (WT + (size_t)z * 1048576) : WoT;

    int r0 = blockIdx.y * 64, c0 = blockIdx.x * 64;
    int rr = t >> 2, cg = (t & 3) * 16;

    #pragma unroll
    for (int u = 0; u < 4; ++u) {
        float4 v = *(const float4*)(src + (size_t)(r0 + rr) * 1024 + c0 + cg + u * 4);
        tile[rr][cg + u * 4 + 0] = v.x;
        tile[rr][cg + u * 4 + 1] = v.y;
        tile[rr][cg + u * 4 + 2] = v.z;
        tile[rr][cg + u * 4 + 3] = v.w;
    }
    __syncthreads();
    bf16x8 o0, o1;
    #pragma unroll
    for (int jj = 0; jj < 8; ++jj) o0[jj] = (__bf16)tile[cg + jj][rr];
    #pragma unroll
    for (int jj = 0; jj < 8; ++jj) o1[jj] = (__bf16)tile[cg + 8 + jj][rr];
    __bf16* dp = dst + (size_t)(c0 + rr) * 1024 + r0 + cg;
    *(bf16x8*)dp = o0;
    *(bf16x8*)(dp + 8) = o1;
}

// ---------------------------------------------------------------------------
// bf16 MFMA GEMM, 128x128 tile, BK=32, ping-pong LDS dbuf (1 barrier/iter),
// bf16 A staging (fp32 cast done in prep — folding it in doubled FETCH and
// VGPRs and cost 3x in round 6). Operand-SWAPPED MFMA for Q/K/out so the
// C-fragment reg-contiguity lands on the output-contiguous dim (vector
// stores); V keeps unswapped orientation for its [ch][s] layout.
// ---------------------------------------------------------------------------
__global__ __launch_bounds__(256) void gemm_bt(
    const __bf16* __restrict__ A, const __bf16* __restrict__ Bt, int mode,
    __bf16* __restrict__ qb, __bf16* __restrict__ kb, __bf16* __restrict__ vb,
    const float* __restrict__ bq, const float* __restrict__ bk,
    const float* __restrict__ bv,
    float* __restrict__ outf, const float* __restrict__ bo)
{
    __shared__ __align__(16) __bf16 As[2][128][32];
    __shared__ __align__(16) __bf16 Bs[2][128][32];

    const int t = threadIdx.x;
    const int wave = t >> 6, lane = t & 63;
    const int quad = lane >> 4, l16 = lane & 15;
    const int wm = wave >> 1, wn = wave & 1;
    const int m0 = blockIdx.y * 128, n0 = blockIdx.x * 128;

    const int sr = t >> 2;          // staging row 0..63
    const int sc = (t & 3) * 8;     // staging col (elements)

    const int z = (mode == 0) ? (n0 >> 10) : 3;
    const bool swp = (z != 2);      // V keeps unswapped orientation

    f32x4 acc[4][4];
    #pragma unroll
    for (int i = 0; i < 4; ++i)
        #pragma unroll
        for (int j = 0; j < 4; ++j) acc[i][j] = (f32x4){0.f, 0.f, 0.f, 0.f};

    const __bf16* pa0 = A + (size_t)(m0 + sr) * 1024 + sc;
    const __bf16* pa1 = A + (size_t)(m0 + sr + 64) * 1024 + sc;
    const __bf16* pb0 = Bt + (size_t)(n0 + sr) * 1024 + sc;
    const __bf16* pb1 = Bt + (size_t)(n0 + sr + 64) * 1024 + sc;

    bf16x8 ra0 = *(const bf16x8*)(pa0);
    bf16x8 ra1 = *(const bf16x8*)(pa1);
    bf16x8 rb0 = *(const bf16x8*)(pb0);
    bf16x8 rb1 = *(const bf16x8*)(pb1);

    for (int k0 = 0; k0 < 1024; k0 += 32) {
        const int p = (k0 >> 5) & 1;
        *(bf16x8*)&As[p][sr][sc] = ra0;
        *(bf16x8*)&As[p][sr + 64][sc] = ra1;
        *(bf16x8*)&Bs[p][sr][sc] = rb0;
        *(bf16x8*)&Bs[p][sr + 64][sc] = rb1;
        __syncthreads();

        const int kn = k0 + 32;
        if (kn < 1024) {   // issue next chunk's loads; overlap compute below
            ra0 = *(const bf16x8*)(pa0 + kn);
            ra1 = *(const bf16x8*)(pa1 + kn);
            rb0 = *(const bf16x8*)(pb0 + kn);
            rb1 = *(const bf16x8*)(pb1 + kn);
        }

        bf16x8 af[4], bfr[4];
        #pragma unroll
        for (int i = 0; i < 4; ++i)
            af[i] = *(const bf16x8*)&As[p][wm * 64 + i * 16 + l16][quad * 8];
        #pragma unroll
        for (int j = 0; j < 4; ++j)
            bfr[j] = *(const bf16x8*)&Bs[p][wn * 64 + j * 16 + l16][quad * 8];
        if (swp) {
            #pragma unroll
            for (int i = 0; i < 4; ++i)
                #pragma unroll
                for (int j = 0; j < 4; ++j)
                    acc[i][j] = MFMA16(bfr[j], af[i], acc[i][j]);   // D[n][m]
        } else {
            #pragma unroll
            for (int i = 0; i < 4; ++i)
                #pragma unroll
                for (int j = 0; j < 4; ++j)
                    acc[i][j] = MFMA16(af[i], bfr[j], acc[i][j]);   // D[m][n]
        }
    }

    if (mode == 0) {
        if (z < 2) {
            // swapped: reg r -> ch+r (contiguous), l16 -> token s
            const float* bias = (z == 0) ? bq : bk;
            __bf16* dst0 = (z == 0) ? qb : kb;
            const float sc2 = (z == 0) ? 0.125f : 1.0f;
            const int h = ((n0 & 1023) >> 6) + wn;
            #pragma unroll
            for (int i = 0; i < 4; ++i) {
                int m = m0 + wm * 64 + i * 16 + l16;
                int b = m >> 10, s = m & 1023;
                __bf16* dst = dst0 + ((size_t)(b * Hh + h) * Ss + s) * Kk;
                #pragma unroll
                for (int j = 0; j < 4; ++j) {
                    int ch0 = j * 16 + quad * 4;
                    float4 b4 = *(const float4*)(bias + (n0 & 1023) + wn * 64 + ch0);
                    bf16x4 o;
                    o[0] = (__bf16)((acc[i][j][0] + b4.x) * sc2);
                    o[1] = (__bf16)((acc[i][j][1] + b4.y) * sc2);
                    o[2] = (__bf16)((acc[i][j][2] + b4.z) * sc2);
                    o[3] = (__bf16)((acc[i][j][3] + b4.w) * sc2);
                    *(bf16x4*)(dst + ch0) = o;
                }
            }
        } else {
            // unswapped (V): reg r -> token s+r (contiguous in [ch][s] layout)
            #pragma unroll
            for (int i = 0; i < 4; ++i) {
                int row = m0 + wm * 64 + i * 16 + quad * 4;
                int b = row >> 10, s = row & 1023;
                #pragma unroll
                for (int j = 0; j < 4; ++j) {
                    int n1 = (n0 + wn * 64 + j * 16 + l16) & 1023;
                    int h = n1 >> 6, ch = n1 & 63;
                    float bia = bv[n1];
                    bf16x4 o;
                    #pragma unroll
                    for (int r = 0; r < 4; ++r) o[r] = (__bf16)(acc[i][j][r] + bia);
                    *(bf16x4*)(vb + ((size_t)(b * Hh + h) * Kk + ch) * Ss + s) = o;
                }
            }
        }
    } else {
        // swapped: reg r -> d+r contiguous -> float4 stores
        #pragma unroll
        for (int i = 0; i < 4; ++i) {
            int m = m0 + wm * 64 + i * 16 + l16;
            #pragma unroll
            for (int j = 0; j < 4; ++j) {
                int n = n0 + wn * 64 + j * 16 + quad * 4;
                float4 b4 = *(const float4*)(bo + n);
                float4 o;
                o.x = acc[i][j][0] + b4.x;
                o.y = acc[i][j][1] + b4.y;
                o.z = acc[i][j][2] + b4.z;
                o.w = acc[i][j][3] + b4.w;
                *(float4*)(outf + (size_t)m * 1024 + n) = o;
            }
        }
    }
}

// ---------------------------------------------------------------------------
// Flash attention: fixed-base softmax, wave-private P, 32 q/wave, direct
// global Q fragments (no Qs tile), bf16 mask, swapped PV (O ch-major ->
// bf16x4 ctx stores). LDS 38.5 KB -> 4 blocks/CU.
// ---------------------------------------------------------------------------
__global__ __launch_bounds__(256) void attn(
    const __bf16* __restrict__ qb, const __bf16* __restrict__ kb,
    const __bf16* __restrict__ vb, const int* __restrict__ mask,
    __bf16* __restrict__ ctx)
{
    const int bh = blockIdx.x;
    const int q0 = blockIdx.y * 128;
    const int b  = bh >> 4;
    const int h  = bh & 15;
    const size_t base = (size_t)bh * Ss * Kk;

    __shared__ __align__(16) __bf16 Ks[64][72];
    __shared__ __align__(16) __bf16 VTs[64][72];
    __shared__ __align__(16) __bf16 Ps[4][32][72];
    __shared__ __bf16 mkb[1024];
    __shared__ float  lds_l[4][32];

    const int t    = threadIdx.x;
    const int wave = t >> 6, lane = t & 63;
    const int quad = lane >> 4, l16 = lane & 15;
    const int qbase = wave * 32;

    {
        int4 mi = *(const int4*)(mask + b * Ss + t * 4);
        mkb[t * 4 + 0] = (__bf16)(float)mi.x;
        mkb[t * 4 + 1] = (__bf16)(float)mi.y;
        mkb[t * 4 + 2] = (__bf16)(float)mi.z;
        mkb[t * 4 + 3] = (__bf16)(float)mi.w;
    }

    const int r0 = t >> 3, c0 = (t & 7) * 8;
    bf16x8 kr0, kr1, vr0, vr1;
    kr0 = *(const bf16x8*)(kb + base + (size_t)(r0) * Kk + c0);
    kr1 = *(const bf16x8*)(kb + base + (size_t)(r0 + 32) * Kk + c0);
    vr0 = *(const bf16x8*)(vb + base + (size_t)(r0) * Ss + c0);
    vr1 = *(const bf16x8*)(vb + base + (size_t)(r0 + 32) * Ss + c0);

    bf16x8 aq[2][2];
    #pragma unroll
    for (int rg = 0; rg < 2; ++rg) {
        const __bf16* qr = qb + base + (size_t)(q0 + qbase + rg * 16 + l16) * Kk;
        aq[rg][0] = *(const bf16x8*)(qr + quad * 8);
        aq[rg][1] = *(const bf16x8*)(qr + 32 + quad * 8);
    }

    __syncthreads();   // mkb visible

    float mqf[2][4], omqf[2][4];
    #pragma unroll
    for (int rg = 0; rg < 2; ++rg)
        #pragma unroll
        for (int i = 0; i < 4; ++i) {
            float m = (float)mkb[q0 + qbase + rg * 16 + quad * 4 + i];
            mqf[rg][i] = m; omqf[rg][i] = 1.0f - m;
        }

    f32x4 O[2][4];     // swapped PV: m=ch(nb*16+quad*4+r), n=q(l16)
    float lsum[2][4];
    #pragma unroll
    for (int rg = 0; rg < 2; ++rg)
        #pragma unroll
        for (int nb = 0; nb < 4; ++nb) O[rg][nb] = (f32x4){0.f, 0.f, 0.f, 0.f};
    #pragma unroll
    for (int rg = 0; rg < 2; ++rg)
        #pragma unroll
        for (int i = 0; i < 4; ++i) lsum[rg][i] = 0.f;

    for (int kt = 0; kt < Ss; kt += 64) {
        __syncthreads();
        *(bf16x8*)&Ks[r0][c0] = kr0;
        *(bf16x8*)&Ks[r0 + 32][c0] = kr1;
        *(bf16x8*)&VTs[r0][c0] = vr0;
        *(bf16x8*)&VTs[r0 + 32][c0] = vr1;
        __syncthreads();

        int ktn = kt + 64;
        if (ktn < Ss) {
            kr0 = *(const bf16x8*)(kb + base + (size_t)(ktn + r0) * Kk + c0);
            kr1 = *(const bf16x8*)(kb + base + (size_t)(ktn + r0 + 32) * Kk + c0);
            vr0 = *(const bf16x8*)(vb + base + (size_t)(r0) * Ss + ktn + c0);
            vr1 = *(const bf16x8*)(vb + base + (size_t)(r0 + 32) * Ss + ktn + c0);
        }

        float mkv[4];
        #pragma unroll
        for (int nb = 0; nb < 4; ++nb) mkv[nb] = (float)mkb[kt + nb * 16 + l16];

        bf16x8 kb0[4], kb1[4];
        #pragma unroll
        for (int nb = 0; nb < 4; ++nb) {
            kb0[nb] = *(const bf16x8*)&Ks[nb * 16 + l16][quad * 8];
            kb1[nb] = *(const bf16x8*)&Ks[nb * 16 + l16][32 + quad * 8];
        }

        f32x4 s[2][4];
        #pragma unroll
        for (int rg = 0; rg < 2; ++rg)
            #pragma unroll
            for (int nb = 0; nb < 4; ++nb) {
                f32x4 a = (f32x4){0.f, 0.f, 0.f, 0.f};
                a = MFMA16(aq[rg][0], kb0[nb], a);
                a = MFMA16(aq[rg][1], kb1[nb], a);
                s[rg][nb] = a;
            }

        // fixed-base softmax: p = mq ? (mk ? exp(s) : 0) : 1
        #pragma unroll
        for (int rg = 0; rg < 2; ++rg)
            #pragma unroll
            for (int i = 0; i < 4; ++i) {
                float ls = 0.f;
                #pragma unroll
                for (int nb = 0; nb < 4; ++nb) {
                    float p = __expf(s[rg][nb][i]) * mkv[nb];
                    p = p * mqf[rg][i] + omqf[rg][i];
                    Ps[wave][rg * 16 + quad * 4 + i][nb * 16 + l16] = (__bf16)p;
                    ls += p;
                }
                lsum[rg][i] += ls;
            }

        bf16x8 ap0[2], ap1[2];
        #pragma unroll
        for (int rg = 0; rg < 2; ++rg) {
            ap0[rg] = *(const bf16x8*)&Ps[wave][rg * 16 + l16][quad * 8];
            ap1[rg] = *(const bf16x8*)&Ps[wave][rg * 16 + l16][32 + quad * 8];
        }
        #pragma unroll
        for (int nb = 0; nb < 4; ++nb) {
            bf16x8 vb0 = *(const bf16x8*)&VTs[nb * 16 + l16][quad * 8];
            bf16x8 vb1 = *(const bf16x8*)&VTs[nb * 16 + l16][32 + quad * 8];
            #pragma unroll
            for (int rg = 0; rg < 2; ++rg) {
                O[rg][nb] = MFMA16(vb0, ap0[rg], O[rg][nb]);
                O[rg][nb] = MFMA16(vb1, ap1[rg], O[rg][nb]);
            }
        }
    }

    #pragma unroll
    for (int rg = 0; rg < 2; ++rg)
        #pragma unroll
        for (int i = 0; i < 4; ++i) {
            float l = lsum[rg][i];
            l += __shfl_xor(l, 1);
            l += __shfl_xor(l, 2);
            l += __shfl_xor(l, 4);
            l += __shfl_xor(l, 8);
            if (l16 == 0) lds_l[wave][rg * 16 + quad * 4 + i] = l;
        }
    float invl[2];
    #pragma unroll
    for (int rg = 0; rg < 2; ++rg) invl[rg] = 1.0f / lds_l[wave][rg * 16 + l16];

    #pragma unroll
    for (int rg = 0; rg < 2; ++rg) {
        int q = q0 + qbase + rg * 16 + l16;
        __bf16* dst = ctx + ((size_t)(b * Ss + q) * Hh + h) * Kk;
        #pragma unroll
        for (int nb = 0; nb < 4; ++nb) {
            bf16x4 o;
            o[0] = (__bf16)(O[rg][nb][0] * invl[rg]);
            o[1] = (__bf16)(O[rg][nb][1] * invl[rg]);
            o[2] = (__bf16)(O[rg][nb][2] * invl[rg]);
            o[3] = (__bf16)(O[rg][nb][3] * invl[rg]);
            *(bf16x4*)(dst + nb * 16 + quad * 4) = o;
        }
    }
}

extern "C" void kernel_launch(void* const* d_in, const int* in_sizes, int n_in,
                              void* d_out, int out_size, void* d_ws, size_t ws_size,
                              hipStream_t stream) {
    const float* x    = (const float*)d_in[0];
    const int*   mask = (const int*)d_in[1];
    const float* Wq   = (const float*)d_in[2];
    const float* bq   = (const float*)d_in[3];
    const float* Wk   = (const float*)d_in[4];
    const float* bk   = (const float*)d_in[5];
    const float* Wv   = (const float*)d_in[6];
    const float* bv   = (const float*)d_in[7];
    const float* Wo   = (const float*)d_in[8];
    const float* bo   = (const float*)d_in[9];

    __bf16* xb   = (__bf16*)d_ws;
    __bf16* WT   = xb + XB_E;
    __bf16* WoT  = WT + WT_E;
    __bf16* qb   = WoT + WOT_E;
    __bf16* kb   = qb + QKV_E;
    __bf16* vb   = kb + QKV_E;
    __bf16* ctxb = vb + QKV_E;
    float* out = (float*)d_out;

    prep<<<dim3(16, 16, 5), 256, 0, stream>>>(x, Wq, Wk, Wv, Wo, xb, WT, WoT);
    gemm_bt<<<dim3(24, 64), 256, 0, stream>>>(xb, WT, 0, qb, kb, vb,
                                              bq, bk, bv, nullptr, nullptr);
    attn<<<dim3(128, 8), 256, 0, stream>>>(qb, kb, vb, mask, ctxb);
    gemm_bt<<<dim3(8, 64), 256, 0, stream>>>(ctxb, WoT, 1, nullptr, nullptr,
                                             nullptr, nullptr, nullptr, nullptr,
                                             out, bo);
}

// Round 8
// 292.505 us; speedup vs baseline: 1.4925x; 1.1464x over previous
//
#include <hip/hip_runtime.h>
#include <math.h>

#define Ss 1024
#define Dd 1024
#define Hh 16
#define Kk 64

typedef __bf16 bf16x8 __attribute__((ext_vector_type(8)));
typedef __bf16 bf16x4 __attribute__((ext_vector_type(4)));
typedef float  f32x4  __attribute__((ext_vector_type(4)));

#define MFMA16(a, b, c) __builtin_amdgcn_mfma_f32_16x16x32_bf16(a, b, c, 0, 0, 0)

// ws element offsets (bf16 units): xb | WT | WoT | qb | kb | vb | ctxb
#define XB_E   8388608u
#define WT_E   3145728u
#define WOT_E  1048576u
#define QKV_E  8388608u

// ---------------------------------------------------------------------------
// prep: z<4 -> transpose+cast weight matrix z; z==4 -> cast x to bf16
// ---------------------------------------------------------------------------
__global__ __launch_bounds__(256) void prep(
    const float* __restrict__ x,
    const float* __restrict__ Wq, const float* __restrict__ Wk,
    const float* __restrict__ Wv, const float* __restrict__ Wo,
    __bf16* __restrict__ xb, __bf16* __restrict__ WT, __bf16* __restrict__ WoT)
{
    __shared__ float tile[64][65];
    const int z = blockIdx.z;
    const int t = threadIdx.x;

    if (z == 4) {   // x cast
        size_t blk = blockIdx.y * 16 + blockIdx.x;
        const float4* src = (const float4*)(x + blk * 32768);
        bf16x4* dst = (bf16x4*)(xb + blk * 32768);
        #pragma unroll
        for (int u = 0; u < 32; ++u) {
            float4 v = src[u * 256 + t];
            dst[u * 256 + t] =
                (bf16x4){(__bf16)v.x, (__bf16)v.y, (__bf16)v.z, (__bf16)v.w};
        }
        return;
    }

    const float* src = (z == 0) ? Wq : (z == 1) ? Wk : (z == 2) ? Wv : Wo;
    __bf16* dst = (z < 3) ? (WT + (size_t)z * 1048576) : WoT;

    int r0 = blockIdx.y * 64, c0 = blockIdx.x * 64;
    int rr = t >> 2, cg = (t & 3) * 16;

    #pragma unroll
    for (int u = 0; u < 4; ++u) {
        float4 v = *(const float4*)(src + (size_t)(r0 + rr) * 1024 + c0 + cg + u * 4);
        tile[rr][cg + u * 4 + 0] = v.x;
        tile[rr][cg + u * 4 + 1] = v.y;
        tile[rr][cg + u * 4 + 2] = v.z;
        tile[rr][cg + u * 4 + 3] = v.w;
    }
    __syncthreads();
    bf16x8 o0, o1;
    #pragma unroll
    for (int jj = 0; jj < 8; ++jj) o0[jj] = (__bf16)tile[cg + jj][rr];
    #pragma unroll
    for (int jj = 0; jj < 8; ++jj) o1[jj] = (__bf16)tile[cg + 8 + jj][rr];
    __bf16* dp = dst + (size_t)(c0 + rr) * 1024 + r0 + cg;
    *(bf16x8*)dp = o0;
    *(bf16x8*)(dp + 8) = o1;
}

// ---------------------------------------------------------------------------
// Compile-time-specialized bf16 MFMA GEMM (KIND: 0=Q,1=K,2=V,3=OUT).
// 128x128 tile, BK=32, ping-pong LDS dbuf (1 barrier/iter), VGPR prefetch.
// Q/K/OUT: operand-swapped MFMA (C reg-contiguity along ch/d -> vector
// stores). V: unswapped (reg-contiguity along s for [ch][s] layout).
// Runtime mode/z branches removed — round 7's dual-path kernel cost 40 VGPRs.
// ---------------------------------------------------------------------------
template<int KIND>
__global__ __launch_bounds__(256) void gemm_k(
    const __bf16* __restrict__ A, const __bf16* __restrict__ Bt,
    __bf16* __restrict__ outb, const float* __restrict__ bias,
    float* __restrict__ outf)
{
    __shared__ __align__(16) __bf16 As[2][128][32];
    __shared__ __align__(16) __bf16 Bs[2][128][32];

    const int t = threadIdx.x;
    const int wave = t >> 6, lane = t & 63;
    const int quad = lane >> 4, l16 = lane & 15;
    const int wm = wave >> 1, wn = wave & 1;
    const int m0 = blockIdx.y * 128, n0 = blockIdx.x * 128;

    const int sr = t >> 2;
    const int sc = (t & 3) * 8;

    f32x4 acc[4][4];
    #pragma unroll
    for (int i = 0; i < 4; ++i)
        #pragma unroll
        for (int j = 0; j < 4; ++j) acc[i][j] = (f32x4){0.f, 0.f, 0.f, 0.f};

    const __bf16* pa0 = A + (size_t)(m0 + sr) * 1024 + sc;
    const __bf16* pa1 = A + (size_t)(m0 + sr + 64) * 1024 + sc;
    const __bf16* pb0 = Bt + (size_t)(n0 + sr) * 1024 + sc;
    const __bf16* pb1 = Bt + (size_t)(n0 + sr + 64) * 1024 + sc;

    bf16x8 ra0 = *(const bf16x8*)(pa0);
    bf16x8 ra1 = *(const bf16x8*)(pa1);
    bf16x8 rb0 = *(const bf16x8*)(pb0);
    bf16x8 rb1 = *(const bf16x8*)(pb1);

    for (int k0 = 0; k0 < 1024; k0 += 32) {
        const int p = (k0 >> 5) & 1;
        *(bf16x8*)&As[p][sr][sc] = ra0;
        *(bf16x8*)&As[p][sr + 64][sc] = ra1;
        *(bf16x8*)&Bs[p][sr][sc] = rb0;
        *(bf16x8*)&Bs[p][sr + 64][sc] = rb1;
        __syncthreads();

        const int kn = k0 + 32;
        if (kn < 1024) {
            ra0 = *(const bf16x8*)(pa0 + kn);
            ra1 = *(const bf16x8*)(pa1 + kn);
            rb0 = *(const bf16x8*)(pb0 + kn);
            rb1 = *(const bf16x8*)(pb1 + kn);
        }

        bf16x8 af[4], bfr[4];
        #pragma unroll
        for (int i = 0; i < 4; ++i)
            af[i] = *(const bf16x8*)&As[p][wm * 64 + i * 16 + l16][quad * 8];
        #pragma unroll
        for (int j = 0; j < 4; ++j)
            bfr[j] = *(const bf16x8*)&Bs[p][wn * 64 + j * 16 + l16][quad * 8];
        if (KIND != 2) {
            #pragma unroll
            for (int i = 0; i < 4; ++i)
                #pragma unroll
                for (int j = 0; j < 4; ++j)
                    acc[i][j] = MFMA16(bfr[j], af[i], acc[i][j]);   // D[n][m]
        } else {
            #pragma unroll
            for (int i = 0; i < 4; ++i)
                #pragma unroll
                for (int j = 0; j < 4; ++j)
                    acc[i][j] = MFMA16(af[i], bfr[j], acc[i][j]);   // D[m][n]
        }
    }

    if (KIND <= 1) {
        // Q/K: swapped; reg r -> ch (contiguous), l16 -> token s
        const float sc2 = (KIND == 0) ? 0.125f : 1.0f;
        const int h = (n0 >> 6) + wn;
        #pragma unroll
        for (int i = 0; i < 4; ++i) {
            int m = m0 + wm * 64 + i * 16 + l16;
            int b = m >> 10, s = m & 1023;
            __bf16* dst = outb + ((size_t)(b * Hh + h) * Ss + s) * Kk;
            #pragma unroll
            for (int j = 0; j < 4; ++j) {
                int ch0 = j * 16 + quad * 4;
                float4 b4 = *(const float4*)(bias + n0 + wn * 64 + ch0);
                bf16x4 o;
                o[0] = (__bf16)((acc[i][j][0] + b4.x) * sc2);
                o[1] = (__bf16)((acc[i][j][1] + b4.y) * sc2);
                o[2] = (__bf16)((acc[i][j][2] + b4.z) * sc2);
                o[3] = (__bf16)((acc[i][j][3] + b4.w) * sc2);
                *(bf16x4*)(dst + ch0) = o;
            }
        }
    } else if (KIND == 2) {
        // V: unswapped; reg r -> token s (contiguous in [ch][s] layout)
        #pragma unroll
        for (int i = 0; i < 4; ++i) {
            int row = m0 + wm * 64 + i * 16 + quad * 4;
            int b = row >> 10, s = row & 1023;
            #pragma unroll
            for (int j = 0; j < 4; ++j) {
                int n1 = n0 + wn * 64 + j * 16 + l16;
                int h = n1 >> 6, ch = n1 & 63;
                float bia = bias[n1];
                bf16x4 o;
                #pragma unroll
                for (int r = 0; r < 4; ++r) o[r] = (__bf16)(acc[i][j][r] + bia);
                *(bf16x4*)(outb + ((size_t)(b * Hh + h) * Kk + ch) * Ss + s) = o;
            }
        }
    } else {
        // OUT: swapped; reg r -> d contiguous -> float4 stores
        #pragma unroll
        for (int i = 0; i < 4; ++i) {
            int m = m0 + wm * 64 + i * 16 + l16;
            #pragma unroll
            for (int j = 0; j < 4; ++j) {
                int n = n0 + wn * 64 + j * 16 + quad * 4;
                float4 b4 = *(const float4*)(bias + n);
                float4 o;
                o.x = acc[i][j][0] + b4.x;
                o.y = acc[i][j][1] + b4.y;
                o.z = acc[i][j][2] + b4.z;
                o.w = acc[i][j][3] + b4.w;
                *(float4*)(outf + (size_t)m * 1024 + n) = o;
            }
        }
    }
}

// ---------------------------------------------------------------------------
// Flash attention: fixed-base softmax, wave-private P, 32 q/wave, direct
// global Q fragments, bf16 mask, swapped PV -> bf16x4 ctx stores.
// ---------------------------------------------------------------------------
__global__ __launch_bounds__(256) void attn(
    const __bf16* __restrict__ qb, const __bf16* __restrict__ kb,
    const __bf16* __restrict__ vb, const int* __restrict__ mask,
    __bf16* __restrict__ ctx)
{
    const int bh = blockIdx.x;
    const int q0 = blockIdx.y * 128;
    const int b  = bh >> 4;
    const int h  = bh & 15;
    const size_t base = (size_t)bh * Ss * Kk;

    __shared__ __align__(16) __bf16 Ks[64][72];
    __shared__ __align__(16) __bf16 VTs[64][72];
    __shared__ __align__(16) __bf16 Ps[4][32][72];
    __shared__ __bf16 mkb[1024];
    __shared__ float  lds_l[4][32];

    const int t    = threadIdx.x;
    const int wave = t >> 6, lane = t & 63;
    const int quad = lane >> 4, l16 = lane & 15;
    const int qbase = wave * 32;

    {
        int4 mi = *(const int4*)(mask + b * Ss + t * 4);
        mkb[t * 4 + 0] = (__bf16)(float)mi.x;
        mkb[t * 4 + 1] = (__bf16)(float)mi.y;
        mkb[t * 4 + 2] = (__bf16)(float)mi.z;
        mkb[t * 4 + 3] = (__bf16)(float)mi.w;
    }

    const int r0 = t >> 3, c0 = (t & 7) * 8;
    bf16x8 kr0, kr1, vr0, vr1;
    kr0 = *(const bf16x8*)(kb + base + (size_t)(r0) * Kk + c0);
    kr1 = *(const bf16x8*)(kb + base + (size_t)(r0 + 32) * Kk + c0);
    vr0 = *(const bf16x8*)(vb + base + (size_t)(r0) * Ss + c0);
    vr1 = *(const bf16x8*)(vb + base + (size_t)(r0 + 32) * Ss + c0);

    bf16x8 aq[2][2];
    #pragma unroll
    for (int rg = 0; rg < 2; ++rg) {
        const __bf16* qr = qb + base + (size_t)(q0 + qbase + rg * 16 + l16) * Kk;
        aq[rg][0] = *(const bf16x8*)(qr + quad * 8);
        aq[rg][1] = *(const bf16x8*)(qr + 32 + quad * 8);
    }

    __syncthreads();   // mkb visible

    float mqf[2][4], omqf[2][4];
    #pragma unroll
    for (int rg = 0; rg < 2; ++rg)
        #pragma unroll
        for (int i = 0; i < 4; ++i) {
            float m = (float)mkb[q0 + qbase + rg * 16 + quad * 4 + i];
            mqf[rg][i] = m; omqf[rg][i] = 1.0f - m;
        }

    f32x4 O[2][4];
    float lsum[2][4];
    #pragma unroll
    for (int rg = 0; rg < 2; ++rg)
        #pragma unroll
        for (int nb = 0; nb < 4; ++nb) O[rg][nb] = (f32x4){0.f, 0.f, 0.f, 0.f};
    #pragma unroll
    for (int rg = 0; rg < 2; ++rg)
        #pragma unroll
        for (int i = 0; i < 4; ++i) lsum[rg][i] = 0.f;

    for (int kt = 0; kt < Ss; kt += 64) {
        __syncthreads();
        *(bf16x8*)&Ks[r0][c0] = kr0;
        *(bf16x8*)&Ks[r0 + 32][c0] = kr1;
        *(bf16x8*)&VTs[r0][c0] = vr0;
        *(bf16x8*)&VTs[r0 + 32][c0] = vr1;
        __syncthreads();

        int ktn = kt + 64;
        if (ktn < Ss) {
            kr0 = *(const bf16x8*)(kb + base + (size_t)(ktn + r0) * Kk + c0);
            kr1 = *(const bf16x8*)(kb + base + (size_t)(ktn + r0 + 32) * Kk + c0);
            vr0 = *(const bf16x8*)(vb + base + (size_t)(r0) * Ss + ktn + c0);
            vr1 = *(const bf16x8*)(vb + base + (size_t)(r0 + 32) * Ss + ktn + c0);
        }

        float mkv[4];
        #pragma unroll
        for (int nb = 0; nb < 4; ++nb) mkv[nb] = (float)mkb[kt + nb * 16 + l16];

        bf16x8 kb0[4], kb1[4];
        #pragma unroll
        for (int nb = 0; nb < 4; ++nb) {
            kb0[nb] = *(const bf16x8*)&Ks[nb * 16 + l16][quad * 8];
            kb1[nb] = *(const bf16x8*)&Ks[nb * 16 + l16][32 + quad * 8];
        }

        f32x4 s[2][4];
        #pragma unroll
        for (int rg = 0; rg < 2; ++rg)
            #pragma unroll
            for (int nb = 0; nb < 4; ++nb) {
                f32x4 a = (f32x4){0.f, 0.f, 0.f, 0.f};
                a = MFMA16(aq[rg][0], kb0[nb], a);
                a = MFMA16(aq[rg][1], kb1[nb], a);
                s[rg][nb] = a;
            }

        #pragma unroll
        for (int rg = 0; rg < 2; ++rg)
            #pragma unroll
            for (int i = 0; i < 4; ++i) {
                float ls = 0.f;
                #pragma unroll
                for (int nb = 0; nb < 4; ++nb) {
                    float p = __expf(s[rg][nb][i]) * mkv[nb];
                    p = p * mqf[rg][i] + omqf[rg][i];
                    Ps[wave][rg * 16 + quad * 4 + i][nb * 16 + l16] = (__bf16)p;
                    ls += p;
                }
                lsum[rg][i] += ls;
            }

        bf16x8 ap0[2], ap1[2];
        #pragma unroll
        for (int rg = 0; rg < 2; ++rg) {
            ap0[rg] = *(const bf16x8*)&Ps[wave][rg * 16 + l16][quad * 8];
            ap1[rg] = *(const bf16x8*)&Ps[wave][rg * 16 + l16][32 + quad * 8];
        }
        #pragma unroll
        for (int nb = 0; nb < 4; ++nb) {
            bf16x8 vb0 = *(const bf16x8*)&VTs[nb * 16 + l16][quad * 8];
            bf16x8 vb1 = *(const bf16x8*)&VTs[nb * 16 + l16][32 + quad * 8];
            #pragma unroll
            for (int rg = 0; rg < 2; ++rg) {
                O[rg][nb] = MFMA16(vb0, ap0[rg], O[rg][nb]);
                O[rg][nb] = MFMA16(vb1, ap1[rg], O[rg][nb]);
            }
        }
    }

    #pragma unroll
    for (int rg = 0; rg < 2; ++rg)
        #pragma unroll
        for (int i = 0; i < 4; ++i) {
            float l = lsum[rg][i];
            l += __shfl_xor(l, 1);
            l += __shfl_xor(l, 2);
            l += __shfl_xor(l, 4);
            l += __shfl_xor(l, 8);
            if (l16 == 0) lds_l[wave][rg * 16 + quad * 4 + i] = l;
        }
    float invl[2];
    #pragma unroll
    for (int rg = 0; rg < 2; ++rg) invl[rg] = 1.0f / lds_l[wave][rg * 16 + l16];

    #pragma unroll
    for (int rg = 0; rg < 2; ++rg) {
        int q = q0 + qbase + rg * 16 + l16;
        __bf16* dst = ctx + ((size_t)(b * Ss + q) * Hh + h) * Kk;
        #pragma unroll
        for (int nb = 0; nb < 4; ++nb) {
            bf16x4 o;
            o[0] = (__bf16)(O[rg][nb][0] * invl[rg]);
            o[1] = (__bf16)(O[rg][nb][1] * invl[rg]);
            o[2] = (__bf16)(O[rg][nb][2] * invl[rg]);
            o[3] = (__bf16)(O[rg][nb][3] * invl[rg]);
            *(bf16x4*)(dst + nb * 16 + quad * 4) = o;
        }
    }
}

extern "C" void kernel_launch(void* const* d_in, const int* in_sizes, int n_in,
                              void* d_out, int out_size, void* d_ws, size_t ws_size,
                              hipStream_t stream) {
    const float* x    = (const float*)d_in[0];
    const int*   mask = (const int*)d_in[1];
    const float* Wq   = (const float*)d_in[2];
    const float* bq   = (const float*)d_in[3];
    const float* Wk   = (const float*)d_in[4];
    const float* bk   = (const float*)d_in[5];
    const float* Wv   = (const float*)d_in[6];
    const float* bv   = (const float*)d_in[7];
    const float* Wo   = (const float*)d_in[8];
    const float* bo   = (const float*)d_in[9];

    __bf16* xb   = (__bf16*)d_ws;
    __bf16* WT   = xb + XB_E;
    __bf16* WoT  = WT + WT_E;
    __bf16* qb   = WoT + WOT_E;
    __bf16* kb   = qb + QKV_E;
    __bf16* vb   = kb + QKV_E;
    __bf16* ctxb = vb + QKV_E;
    float* out = (float*)d_out;

    prep<<<dim3(16, 16, 5), 256, 0, stream>>>(x, Wq, Wk, Wv, Wo, xb, WT, WoT);
    gemm_k<0><<<dim3(8, 64), 256, 0, stream>>>(xb, WT, qb, bq, nullptr);
    gemm_k<1><<<dim3(8, 64), 256, 0, stream>>>(xb, WT + 1048576, kb, bk, nullptr);
    gemm_k<2><<<dim3(8, 64), 256, 0, stream>>>(xb, WT + 2097152, vb, bv, nullptr);
    attn<<<dim3(128, 8), 256, 0, stream>>>(qb, kb, vb, mask, ctxb);
    gemm_k<3><<<dim3(8, 64), 256, 0, stream>>>(ctxb, WoT, nullptr, bo, out);
}